// Round 1
// baseline (437.144 us; speedup 1.0000x reference)
//
#include <hip/hip_runtime.h>
#include <hip/hip_bf16.h>

// MultiHeadAttention: x (8,16,2048,128) fp32, Q=K=V=x per (b,s) head.
// 128 heads, N=2048, D=128. SCALE = 1/sqrt(2048*128) = 1/512 exactly.
// Flash-attention, bf16 MFMA 16x16x32, max-free softmax (logits in [-0.15,0.45]).

#define NSEQ   2048
#define DIM    128
#define QBLK   128   // 4 waves x 32 rows
#define KVBLK  64
#define SCALE  (1.0f / 512.0f)

typedef short s4  __attribute__((ext_vector_type(4)));
typedef short s8  __attribute__((ext_vector_type(8)));
typedef float f4  __attribute__((ext_vector_type(4)));

__device__ __forceinline__ short f2bf(float f) {
    union { float f; unsigned int u; } c; c.f = f;
    unsigned int u = c.u;
    u += 0x7fffu + ((u >> 16) & 1u);   // round-to-nearest-even
    return (short)(u >> 16);
}

__global__ __launch_bounds__(256, 2)
void attn_fwd(const float* __restrict__ x, float* __restrict__ out) {
    // XCD-aware swizzle: 2048 blocks, 8 XCDs; keep a head's 16 q-blocks on one XCD.
    const int nwg   = gridDim.x;          // 2048, % 8 == 0 -> bijective
    const int chunk = nwg >> 3;
    const int bid   = blockIdx.x;
    const int wg    = (bid & 7) * chunk + (bid >> 3);
    const int head  = wg >> 4;            // 16 q-blocks per head
    const int qb    = wg & 15;

    const float* __restrict__ xh = x   + (size_t)head * (NSEQ * DIM);
    float* __restrict__       oh = out + (size_t)head * (NSEQ * DIM);
    const int q0 = qb * QBLK;

    const int tid  = threadIdx.x;
    const int lane = tid & 63;
    const int wave = tid >> 6;
    const int g    = lane >> 4;    // 0..3 (16-lane group)
    const int l15  = lane & 15;

    __shared__ short sK [KVBLK * DIM];     // [64][128] row-major, XOR-swizzled
    __shared__ short sVt[DIM * KVBLK];     // [128][64] transposed, XOR-swizzled
    __shared__ short sP [4][32 * KVBLK];   // per-wave [32][64], XOR-swizzled

    // ---- Q fragments (held in registers for the whole kernel) ----
    // Swapped QK^T: Q is the B operand. B-frag: lane holds Q[qt*16+l15][kc*32+g*8 + j]
    const int qw0 = q0 + wave * 32;
    s8 Qf[2][4];
#pragma unroll
    for (int qt = 0; qt < 2; ++qt)
#pragma unroll
        for (int kc = 0; kc < 4; ++kc) {
            const float* p = xh + (size_t)(qw0 + qt * 16 + l15) * DIM + kc * 32 + g * 8;
            f4 a = *(const f4*)p;
            f4 b = *(const f4*)(p + 4);
            s8 q;
            q[0] = f2bf(a[0]); q[1] = f2bf(a[1]); q[2] = f2bf(a[2]); q[3] = f2bf(a[3]);
            q[4] = f2bf(b[0]); q[5] = f2bf(b[1]); q[6] = f2bf(b[2]); q[7] = f2bf(b[3]);
            Qf[qt][kc] = q;
        }

    f4 accO[2][8];
#pragma unroll
    for (int qt = 0; qt < 2; ++qt)
#pragma unroll
        for (int dt = 0; dt < 8; ++dt)
            accO[qt][dt] = (f4){0.f, 0.f, 0.f, 0.f};
    float lsum[2] = {0.f, 0.f};

    // staging assignment: thread owns rows 8*rg..8*rg+7, cols d0..d0+3
    const int rg = tid >> 5;          // 0..7
    const int d0 = (tid & 31) * 4;    // 0..124

    for (int kv0 = 0; kv0 < NSEQ; kv0 += KVBLK) {
        __syncthreads();   // previous tile's LDS reads complete

        // ---- stage K (row-major) + Vt (transposed), fp32 -> bf16 ----
        f4 ld[8];
        const float* src = xh + (size_t)(kv0 + 8 * rg) * DIM + d0;
#pragma unroll
        for (int i = 0; i < 8; ++i) ld[i] = *(const f4*)(src + i * DIM);
#pragma unroll
        for (int i = 0; i < 8; ++i) {   // K row write: 4 consecutive d (8B)
            s4 kv;
            kv[0] = f2bf(ld[i][0]); kv[1] = f2bf(ld[i][1]);
            kv[2] = f2bf(ld[i][2]); kv[3] = f2bf(ld[i][3]);
            const int idx = ((8 * rg + i) * DIM + d0) ^ (i << 3);  // row&7 == i
            *(s4*)&sK[idx] = kv;
        }
#pragma unroll
        for (int j = 0; j < 4; ++j) {   // Vt write: 8 consecutive u (16B)
            s8 vv;
#pragma unroll
            for (int i = 0; i < 8; ++i) vv[i] = f2bf(ld[i][j]);
            const int d   = d0 + j;
            const int idx = (d * KVBLK + 8 * rg) ^ ((d & 7) << 3);
            *(s8*)&sVt[idx] = vv;
        }
        __syncthreads();

        // ---- QK^T (swapped: S^T[u][q] = sum_d K[u][d] Q[q][d]) ----
        f4 accS[2][4];
#pragma unroll
        for (int qt = 0; qt < 2; ++qt)
#pragma unroll
            for (int ut = 0; ut < 4; ++ut)
                accS[qt][ut] = (f4){0.f, 0.f, 0.f, 0.f};

#pragma unroll
        for (int ut = 0; ut < 4; ++ut) {
            s8 Kf[4];
#pragma unroll
            for (int kc = 0; kc < 4; ++kc)
                Kf[kc] = *(const s8*)&sK[(((ut * 16 + l15) * DIM) + kc * 32 + g * 8)
                                         ^ ((l15 & 7) << 3)];
#pragma unroll
            for (int qt = 0; qt < 2; ++qt)
#pragma unroll
                for (int kc = 0; kc < 4; ++kc)
                    accS[qt][ut] = __builtin_amdgcn_mfma_f32_16x16x32_bf16(
                        Kf[kc], Qf[qt][kc], accS[qt][ut], 0, 0, 0);
        }

        // ---- softmax numerator (max-free) + P -> LDS ----
        // lane holds S^T rows u = ut*16 + 4g + reg for column q = qt*16 + l15
#pragma unroll
        for (int qt = 0; qt < 2; ++qt) {
            float part = 0.f;
            const int qrow = qt * 16 + l15;
#pragma unroll
            for (int ut = 0; ut < 4; ++ut) {
                f4 s = accS[qt][ut];
                float p0 = __expf(s[0] * SCALE);
                float p1 = __expf(s[1] * SCALE);
                float p2 = __expf(s[2] * SCALE);
                float p3 = __expf(s[3] * SCALE);
                part += (p0 + p1) + (p2 + p3);
                s4 pb;
                pb[0] = f2bf(p0); pb[1] = f2bf(p1); pb[2] = f2bf(p2); pb[3] = f2bf(p3);
                const int idx = (qrow * KVBLK + ut * 16 + g * 4) ^ ((qrow & 7) << 3);
                *(s4*)&sP[wave][idx] = pb;
            }
            // sum across the 4 lane-groups holding the same q (disjoint u subsets)
            part += __shfl_xor(part, 16);
            part += __shfl_xor(part, 32);
            lsum[qt] += part;
        }

        // ---- PV: O[q][d] += P[q][u] V[u][d] ----
        s8 Pf[2][2];
#pragma unroll
        for (int qt = 0; qt < 2; ++qt)
#pragma unroll
            for (int kc = 0; kc < 2; ++kc)
                Pf[qt][kc] = *(const s8*)&sP[wave][((qt * 16 + l15) * KVBLK + kc * 32 + g * 8)
                                                   ^ ((l15 & 7) << 3)];
#pragma unroll
        for (int dt = 0; dt < 8; ++dt) {
            s8 Vf[2];
#pragma unroll
            for (int kc = 0; kc < 2; ++kc)
                Vf[kc] = *(const s8*)&sVt[((dt * 16 + l15) * KVBLK + kc * 32 + g * 8)
                                          ^ ((l15 & 7) << 3)];
#pragma unroll
            for (int qt = 0; qt < 2; ++qt)
#pragma unroll
                for (int kc = 0; kc < 2; ++kc)
                    accO[qt][dt] = __builtin_amdgcn_mfma_f32_16x16x32_bf16(
                        Pf[qt][kc], Vf[kc], accO[qt][dt], 0, 0, 0);
        }
    }

    // ---- epilogue: divide by softmax denominator, store fp32 ----
    // accO C-layout: row q = qt*16 + 4g + reg, col d = dt*16 + l15.
    // lsum[qt] lives at lanes keyed by l15 == q%16 -> shfl from lane 4g+reg.
#pragma unroll
    for (int qt = 0; qt < 2; ++qt) {
#pragma unroll
        for (int r = 0; r < 4; ++r) {
            const float lq  = __shfl(lsum[qt], 4 * g + r, 64);
            const float inv = 1.f / lq;
            const int qrow  = qw0 + qt * 16 + 4 * g + r;
#pragma unroll
            for (int dt = 0; dt < 8; ++dt)
                oh[(size_t)qrow * DIM + dt * 16 + l15] = accO[qt][dt][r] * inv;
        }
    }
}

extern "C" void kernel_launch(void* const* d_in, const int* in_sizes, int n_in,
                              void* d_out, int out_size, void* d_ws, size_t ws_size,
                              hipStream_t stream) {
    const float* x = (const float*)d_in[0];
    float* out     = (float*)d_out;
    // grid = 128 heads * 16 q-blocks = 2048 blocks of 256 threads
    hipLaunchKernelGGL(attn_fwd, dim3(2048), dim3(256), 0, stream, x, out);
}